// Round 8
// baseline (348.807 us; speedup 1.0000x reference)
//
#include <hip/hip_runtime.h>
#include <cstdint>
#include <cstddef>

#define E_N 500000
#define FD 128
#define TD 100
#define OD 128
#define NT 4
#define IND 228   // FD + TD
#define KP 256    // K padded to MFMA multiple
#define GX 256    // blocks per type for gemm
#define EPS 136   // epilogue LDS row stride in floats

// workspace layout (bytes)
static constexpr size_t BUCKET_OFF = 0;                                   // int[E_N] = 2,000,000
static constexpr size_t WBF_OFF    = 2000000;                             // bf16[NT][OD][KP] = 262,144
static constexpr size_t BIASC_OFF  = WBF_OFF + (size_t)NT * OD * KP * 2;  // float[NT][OD] = 2048
static constexpr size_t CTR_OFF    = BIASC_OFF + (size_t)NT * OD * 4;     // int[16]
static constexpr size_t WS_NEED    = CTR_OFF + 64;

typedef __attribute__((ext_vector_type(8))) short short8;
typedef __attribute__((ext_vector_type(4))) float f32x4;

__device__ __forceinline__ unsigned short f2bf(float x) {
  union { float f; unsigned u; } v; v.f = x;
  unsigned r = v.u + 0x7fff + ((v.u >> 16) & 1);   // RNE, inputs are finite
  return (unsigned short)(r >> 16);
}

// swizzled byte offset into the A tile: row r (0..63), k elem (0..255), bf16.
__device__ __forceinline__ int a_off(int r, int k) {
  return ((r << 9) + (k << 1)) ^ ((r & 7) << 4);
}

// epilogue LDS word offset: row (edge 0..63), slot (16B chunk 0..31 of the row)
__device__ __forceinline__ int ep_w(int row, int slot) {
  return row * EPS + ((slot ^ (row & 7)) << 2);
}

__global__ void init_kernel(int* ctr) {
  if (threadIdx.x < 16) ctr[threadIdx.x] = 0;
}

__global__ void hist_kernel(const int* __restrict__ types, int* __restrict__ counts, int n) {
  __shared__ int lc[NT];
  if (threadIdx.x < NT) lc[threadIdx.x] = 0;
  __syncthreads();
  int i = blockIdx.x * blockDim.x + threadIdx.x;
  int stride = gridDim.x * blockDim.x;
  for (; i < n; i += stride) atomicAdd(&lc[types[i]], 1);
  __syncthreads();
  if (threadIdx.x < NT) atomicAdd(&counts[threadIdx.x], lc[threadIdx.x]);
}

// ctr[0..3]=counts, ctr[4..7]=offsets, ctr[8..11]=cursors. Also fuse bias precompute.
__global__ void scan_bias_kernel(int* __restrict__ ctr, const float* __restrict__ b,
                                 const float* __restrict__ temb, float* __restrict__ biasc) {
  if (threadIdx.x == 0) {
    int off = 0;
    for (int t = 0; t < NT; ++t) { ctr[4 + t] = off; ctr[8 + t] = off; off += ctr[t]; }
  }
  for (int i = threadIdx.x; i < NT * OD; i += blockDim.x) biasc[i] = b[i] + temb[i];
}

// W [NT][IND][OD] f32 -> Wbf [NT][OD][KP] bf16 (N-major, K zero-padded beyond 228)
__global__ void wconv_kernel(const float* __restrict__ W, unsigned short* __restrict__ Wbf) {
  int row = blockIdx.x * 4 + (threadIdx.x >> 6);   // row = t*OD + n, 0..511
  int t = row >> 7, n = row & 127;
  int k0 = (threadIdx.x & 63) << 2;
  ushort4 o;
  float v0 = (k0 + 0 < IND) ? W[((size_t)t * IND + k0 + 0) * OD + n] : 0.f;
  float v1 = (k0 + 1 < IND) ? W[((size_t)t * IND + k0 + 1) * OD + n] : 0.f;
  float v2 = (k0 + 2 < IND) ? W[((size_t)t * IND + k0 + 2) * OD + n] : 0.f;
  float v3 = (k0 + 3 < IND) ? W[((size_t)t * IND + k0 + 3) * OD + n] : 0.f;
  o.x = f2bf(v0); o.y = f2bf(v1); o.z = f2bf(v2); o.w = f2bf(v3);
  *(ushort4*)(Wbf + ((size_t)row << 8) + k0) = o;
}

// ballot-compacted bucket fill (order within type atomics-nondeterministic; output invariant)
__global__ void fill_kernel(const int* __restrict__ types, int* __restrict__ bucket,
                            int* __restrict__ cursors, int n) {
  __shared__ int wcnt[4][NT];
  __shared__ int wbase[4][NT];
  int tid = threadIdx.x, w = tid >> 6, l = tid & 63;
  int i = blockIdx.x * 256 + tid;
  int t = (i < n) ? types[i] : -1;
  unsigned long long m[NT];
  #pragma unroll
  for (int tt = 0; tt < NT; ++tt) m[tt] = __ballot(t == tt);
  if (l == 0) {
    #pragma unroll
    for (int tt = 0; tt < NT; ++tt) wcnt[w][tt] = (int)__popcll(m[tt]);
  }
  __syncthreads();
  if (tid < NT) {
    int tt = tid, s[4], tot = 0;
    #pragma unroll
    for (int w2 = 0; w2 < 4; ++w2) { s[w2] = tot; tot += wcnt[w2][tt]; }
    int base = atomicAdd(&cursors[tt], tot);
    #pragma unroll
    for (int w2 = 0; w2 < 4; ++w2) wbase[w2][tt] = base + s[w2];
  }
  __syncthreads();
  if (t >= 0) {
    int pos = wbase[w][t] + (int)__popcll(m[t] & ((1ull << l) - 1ull));
    bucket[pos] = i;
  }
}

// Main kernel: r4's SYNCHRONOUS phase structure (plain __syncthreads -> stores
// complete compactly, clean full-line L2 evictions; GX=256) combined with the
// swapped-MFMA epilogue (W first operand -> lane holds [edge][4 cols] -> one
// ds_write_b128 per fragment) and register-held edge indices.
__global__ __launch_bounds__(256, 3) void gemm_kernel(
    const float* __restrict__ feats, const float* __restrict__ ts,
    const float* __restrict__ freqs, const unsigned short* __restrict__ Wbf,
    const float* __restrict__ biasc, const int* __restrict__ bucket,
    const int* __restrict__ ctr, float* __restrict__ out) {
  // union: A tile bf16 [64][256] swizzled (32768 B) / epilogue f32 [64][EPS] (34816 B)
  __shared__ __align__(16) char smraw[64 * EPS * 4];
  __shared__ __align__(16) float sfreq[128];

  const int t = blockIdx.y;
  const int cnt = ctr[t];
  const int off = ctr[4 + t];
  const int ntiles = (cnt + 63) >> 6;
  const int chunk = (ntiles + GX - 1) / GX;
  const int t0 = blockIdx.x * chunk;
  const int t1 = min(t0 + chunk, ntiles);
  if (t0 >= t1) return;

  const int tid = threadIdx.x;
  const int wid = tid >> 6, lane = tid & 63;
  const int bl = lane & 15, bh = lane >> 4;
  const int r = tid >> 2, part = tid & 3;   // 4 threads per A-row; part = 32-elem window

  // W fragments, first MFMA operand (A-layout): lane bl <-> out-col, k-window bh*8
  short8 bfrag[8][2];
  #pragma unroll
  for (int n = 0; n < 2; ++n) {
    const unsigned short* bp =
        Wbf + (((size_t)t * OD + wid * 32 + n * 16 + bl) << 8) + (bh << 3);
    #pragma unroll
    for (int k = 0; k < 8; ++k) bfrag[k][n] = *(const short8*)(bp + k * 32);
  }
  // bias for this lane's cols: col = wid*32 + n*16 + bh*4 + j
  const float4 bv0 = *(const float4*)(biasc + t * OD + wid * 32 + bh * 4);
  const float4 bv1 = *(const float4*)(biasc + t * OD + wid * 32 + 16 + bh * 4);

  if (tid < 128) sfreq[tid] = (tid < TD) ? freqs[t * TD + tid] : 0.f;

  auto stage = [&](const float4* p, float tvv) {
    union { unsigned short s[32]; uint4 v4[4]; } pk;
    union { unsigned short s[32]; uint4 v4[4]; } tk;
    #pragma unroll
    for (int c = 0; c < 8; ++c) {
      pk.s[4 * c + 0] = f2bf(p[c].x); pk.s[4 * c + 1] = f2bf(p[c].y);
      pk.s[4 * c + 2] = f2bf(p[c].z); pk.s[4 * c + 3] = f2bf(p[c].w);
    }
    #pragma unroll
    for (int m = 0; m < 8; ++m) {
      float4 fq = *(const float4*)&sfreq[part * 32 + 4 * m];
      tk.s[4 * m + 0] = f2bf(__cosf(tvv * fq.x));
      tk.s[4 * m + 1] = f2bf(__cosf(tvv * fq.y));
      tk.s[4 * m + 2] = f2bf(__cosf(tvv * fq.z));
      tk.s[4 * m + 3] = f2bf(__cosf(tvv * fq.w));
    }
    #pragma unroll
    for (int j = 0; j < 4; ++j)
      *(uint4*)(smraw + a_off(r, part * 32 + 8 * j)) = pk.v4[j];
    #pragma unroll
    for (int j = 0; j < 4; ++j)
      *(uint4*)(smraw + a_off(r, FD + part * 32 + 8 * j)) = tk.v4[j];
  };

  // ---- prologue ----
  int e_cur = -1; float tv_cur = 0.f;
  {
    const int va = min(64, cnt - t0 * 64);
    if (r < va) { e_cur = bucket[off + t0 * 64 + r]; tv_cur = ts[e_cur]; }
  }
  float4 pf[8];
  if (e_cur >= 0) {
    const float4* src = (const float4*)(feats + (size_t)e_cur * FD + part * 32);
    #pragma unroll
    for (int c = 0; c < 8; ++c) pf[c] = src[c];
  }
  int e_b = -1; float tv_b = 0.f;
  if (t0 + 1 < t1) {
    const int vb = min(64, cnt - (t0 + 1) * 64);
    if (r < vb) { e_b = bucket[off + (t0 + 1) * 64 + r]; tv_b = ts[e_b]; }
  }
  __syncthreads();                    // sfreq visible
  if (e_cur >= 0) stage(pf, tv_cur);

  for (int tt = t0; tt < t1; ++tt) {
    const bool last = (tt == t1 - 1);
    __syncthreads();   // A(tt) ready

    // prefetch feats(tt+1) -> regs; drains at the post-MFMA barrier (rides under MFMA)
    if (!last && e_b >= 0) {
      const float4* src = (const float4*)(feats + (size_t)e_b * FD + part * 32);
      #pragma unroll
      for (int c = 0; c < 8; ++c) pf[c] = src[c];
    }
    // issue idx(tt+2): bucket->ts chain covered by a full iteration
    int e_c = -1; float tv_c = 0.f;
    if (tt + 2 < t1) {
      const int vc = min(64, cnt - (tt + 2) * 64);
      if (r < vc) { e_c = bucket[off + (tt + 2) * 64 + r]; tv_c = ts[e_c]; }
    }

    // ---- MFMA, bias in acc-init ----
    f32x4 acc[4][2];
    #pragma unroll
    for (int rt = 0; rt < 4; ++rt) {
      acc[rt][0][0] = bv0.x; acc[rt][0][1] = bv0.y; acc[rt][0][2] = bv0.z; acc[rt][0][3] = bv0.w;
      acc[rt][1][0] = bv1.x; acc[rt][1][1] = bv1.y; acc[rt][1][2] = bv1.z; acc[rt][1][3] = bv1.w;
    }
    __builtin_amdgcn_s_setprio(1);
    #pragma unroll
    for (int rt = 0; rt < 4; ++rt) {
      #pragma unroll
      for (int k = 0; k < 8; ++k) {
        short8 av = *(const short8*)(smraw + a_off(rt * 16 + bl, k * 32 + bh * 8));
        acc[rt][0] = __builtin_amdgcn_mfma_f32_16x16x32_bf16(bfrag[k][0], av, acc[rt][0], 0, 0, 0);
        acc[rt][1] = __builtin_amdgcn_mfma_f32_16x16x32_bf16(bfrag[k][1], av, acc[rt][1], 0, 0, 0);
      }
    }
    __builtin_amdgcn_s_setprio(0);
    __syncthreads();   // A reads done; prefetch drained; region reusable

    // ---- epilogue write: lane -> row rt*16+bl, slot wid*8+n*4+bh, one b128 each ----
    float* ep = (float*)smraw;
    #pragma unroll
    for (int rt = 0; rt < 4; ++rt) {
      *(f32x4*)(ep + ep_w(rt * 16 + bl, wid * 8 + 0 * 4 + bh)) = acc[rt][0];
      *(f32x4*)(ep + ep_w(rt * 16 + bl, wid * 8 + 1 * 4 + bh)) = acc[rt][1];
    }
    __syncthreads();   // epilogue visible

    // ---- store: thread owns its row's cols part*32..+31 (full-line pattern) ----
    if (e_cur >= 0) {
      float* dst = out + (size_t)e_cur * OD + part * 32;
      #pragma unroll
      for (int c = 0; c < 8; ++c) {
        f32x4 v = *(const f32x4*)(ep + ep_w(r, part * 8 + c));
        *(f32x4*)(dst + 4 * c) = v;
      }
    }

    if (!last) {
      __syncthreads();   // ep reads done; stores drained compactly (clean L2 evictions)
      if (e_b >= 0) stage(pf, tv_b);
      e_cur = e_b; tv_cur = tv_b;
      e_b = e_c; tv_b = tv_c;
    }
  }
}

// correctness fallback if ws is too small for bucketing (fp32 vector path)
__global__ void naive_kernel(const float* __restrict__ feats, const float* __restrict__ ts,
                             const int* __restrict__ types, const float* __restrict__ W,
                             const float* __restrict__ b, const float* __restrict__ temb,
                             const float* __restrict__ freqs, float* __restrict__ out) {
  __shared__ float comb[IND];
  int e = blockIdx.x;
  int t = types[e];
  int tid = threadIdx.x;  // 128 threads
  comb[tid] = feats[(size_t)e * FD + tid];
  if (tid < TD) comb[FD + tid] = __cosf(ts[e] * freqs[t * TD + tid]);
  __syncthreads();
  float acc = b[t * OD + tid] + temb[t * OD + tid];
  for (int k = 0; k < IND; ++k) acc += comb[k] * W[((size_t)t * IND + k) * OD + tid];
  out[(size_t)e * OD + tid] = acc;
}

extern "C" void kernel_launch(void* const* d_in, const int* in_sizes, int n_in,
                              void* d_out, int out_size, void* d_ws, size_t ws_size,
                              hipStream_t stream) {
  const float* feats = (const float*)d_in[0];
  const float* ts    = (const float*)d_in[1];
  const int*   types = (const int*)d_in[2];
  const float* W     = (const float*)d_in[3];
  const float* bb    = (const float*)d_in[4];
  const float* temb  = (const float*)d_in[5];
  const float* freqs = (const float*)d_in[6];
  float* out = (float*)d_out;

  if (ws_size < WS_NEED) {
    naive_kernel<<<E_N, 128, 0, stream>>>(feats, ts, types, W, bb, temb, freqs, out);
    return;
  }

  char* ws = (char*)d_ws;
  int* bucket = (int*)(ws + BUCKET_OFF);
  unsigned short* Wbf = (unsigned short*)(ws + WBF_OFF);
  float* biasc = (float*)(ws + BIASC_OFF);
  int* ctr = (int*)(ws + CTR_OFF);

  init_kernel<<<1, 16, 0, stream>>>(ctr);
  hist_kernel<<<1024, 256, 0, stream>>>(types, ctr, E_N);
  scan_bias_kernel<<<1, 256, 0, stream>>>(ctr, bb, temb, biasc);
  wconv_kernel<<<(NT * OD) / 4, 256, 0, stream>>>(W, Wbf);
  fill_kernel<<<(E_N + 255) / 256, 256, 0, stream>>>(types, bucket, ctr + 8, E_N);
  dim3 g(GX, NT);
  gemm_kernel<<<g, 256, 0, stream>>>(feats, ts, freqs, Wbf, biasc, bucket, ctr, out);
}

// Round 9
// 205.801 us; speedup vs baseline: 1.6949x; 1.6949x over previous
//
#include <hip/hip_runtime.h>
#include <cstdint>
#include <cstddef>

#define E_N 500000
#define FD 128
#define TD 100
#define OD 128
#define NT 4
#define IND 228   // FD + TD
#define KP 256    // K padded to MFMA multiple
#define GX 256    // blocks per type for gemm
#define EPS 136   // epilogue LDS row stride in floats

// workspace layout (bytes)
static constexpr size_t BUCKET_OFF = 0;                                   // int[E_N] = 2,000,000
static constexpr size_t WBF_OFF    = 2000000;                             // bf16[NT][OD][KP] = 262,144
static constexpr size_t BIASC_OFF  = WBF_OFF + (size_t)NT * OD * KP * 2;  // float[NT][OD] = 2048
static constexpr size_t CTR_OFF    = BIASC_OFF + (size_t)NT * OD * 4;     // int[16]
static constexpr size_t WS_NEED    = CTR_OFF + 64;

typedef __attribute__((ext_vector_type(8))) short short8;
typedef __attribute__((ext_vector_type(4))) float f32x4;

__device__ __forceinline__ unsigned short f2bf(float x) {
  union { float f; unsigned u; } v; v.f = x;
  unsigned r = v.u + 0x7fff + ((v.u >> 16) & 1);   // RNE, inputs are finite
  return (unsigned short)(r >> 16);
}

// swizzled byte offset into the A tile: row r (0..63), k elem (0..255), bf16.
__device__ __forceinline__ int a_off(int r, int k) {
  return ((r << 9) + (k << 1)) ^ ((r & 7) << 4);
}

// epilogue LDS word offset: row (edge 0..63), slot (16B chunk 0..31 of the row)
__device__ __forceinline__ int ep_w(int row, int slot) {
  return row * EPS + ((slot ^ (row & 7)) << 2);
}

__global__ void init_kernel(int* ctr) {
  if (threadIdx.x < 16) ctr[threadIdx.x] = 0;
}

__global__ void hist_kernel(const int* __restrict__ types, int* __restrict__ counts, int n) {
  __shared__ int lc[NT];
  if (threadIdx.x < NT) lc[threadIdx.x] = 0;
  __syncthreads();
  int i = blockIdx.x * blockDim.x + threadIdx.x;
  int stride = gridDim.x * blockDim.x;
  for (; i < n; i += stride) atomicAdd(&lc[types[i]], 1);
  __syncthreads();
  if (threadIdx.x < NT) atomicAdd(&counts[threadIdx.x], lc[threadIdx.x]);
}

// ctr[0..3]=counts, ctr[4..7]=offsets, ctr[8..11]=cursors. Also fuse bias precompute.
__global__ void scan_bias_kernel(int* __restrict__ ctr, const float* __restrict__ b,
                                 const float* __restrict__ temb, float* __restrict__ biasc) {
  if (threadIdx.x == 0) {
    int off = 0;
    for (int t = 0; t < NT; ++t) { ctr[4 + t] = off; ctr[8 + t] = off; off += ctr[t]; }
  }
  for (int i = threadIdx.x; i < NT * OD; i += blockDim.x) biasc[i] = b[i] + temb[i];
}

// W [NT][IND][OD] f32 -> Wbf [NT][OD][KP] bf16 (N-major, K zero-padded beyond 228)
__global__ void wconv_kernel(const float* __restrict__ W, unsigned short* __restrict__ Wbf) {
  int row = blockIdx.x * 4 + (threadIdx.x >> 6);   // row = t*OD + n, 0..511
  int t = row >> 7, n = row & 127;
  int k0 = (threadIdx.x & 63) << 2;
  ushort4 o;
  float v0 = (k0 + 0 < IND) ? W[((size_t)t * IND + k0 + 0) * OD + n] : 0.f;
  float v1 = (k0 + 1 < IND) ? W[((size_t)t * IND + k0 + 1) * OD + n] : 0.f;
  float v2 = (k0 + 2 < IND) ? W[((size_t)t * IND + k0 + 2) * OD + n] : 0.f;
  float v3 = (k0 + 3 < IND) ? W[((size_t)t * IND + k0 + 3) * OD + n] : 0.f;
  o.x = f2bf(v0); o.y = f2bf(v1); o.z = f2bf(v2); o.w = f2bf(v3);
  *(ushort4*)(Wbf + ((size_t)row << 8) + k0) = o;
}

// ballot-compacted bucket fill (order within type atomics-nondeterministic; output invariant)
__global__ void fill_kernel(const int* __restrict__ types, int* __restrict__ bucket,
                            int* __restrict__ cursors, int n) {
  __shared__ int wcnt[4][NT];
  __shared__ int wbase[4][NT];
  int tid = threadIdx.x, w = tid >> 6, l = tid & 63;
  int i = blockIdx.x * 256 + tid;
  int t = (i < n) ? types[i] : -1;
  unsigned long long m[NT];
  #pragma unroll
  for (int tt = 0; tt < NT; ++tt) m[tt] = __ballot(t == tt);
  if (l == 0) {
    #pragma unroll
    for (int tt = 0; tt < NT; ++tt) wcnt[w][tt] = (int)__popcll(m[tt]);
  }
  __syncthreads();
  if (tid < NT) {
    int tt = tid, s[4], tot = 0;
    #pragma unroll
    for (int w2 = 0; w2 < 4; ++w2) { s[w2] = tot; tot += wcnt[w2][tt]; }
    int base = atomicAdd(&cursors[tt], tot);
    #pragma unroll
    for (int w2 = 0; w2 < 4; ++w2) wbase[w2][tt] = base + s[w2];
  }
  __syncthreads();
  if (t >= 0) {
    int pos = wbase[w][t] + (int)__popcll(m[t] & ((1ull << l) - 1ull));
    bucket[pos] = i;
  }
}

// Main kernel: synchronous phase structure (plain __syncthreads, GX=256) +
// swapped-MFMA epilogue (lane holds [edge][4 cols] -> one ds_write_b128 each).
// NOTE: no min-waves arg in __launch_bounds__ -- capping to 3 waves/EU forced
// VGPR=84 in r5-r8, spilling pf/bfrag/acc to scratch (global), which inflated
// FETCH+WRITE by ~140 MB each and caused the 226-865 us regressions.
__global__ __launch_bounds__(256) void gemm_kernel(
    const float* __restrict__ feats, const float* __restrict__ ts,
    const float* __restrict__ freqs, const unsigned short* __restrict__ Wbf,
    const float* __restrict__ biasc, const int* __restrict__ bucket,
    const int* __restrict__ ctr, float* __restrict__ out) {
  // union: A tile bf16 [64][256] swizzled (32768 B) / epilogue f32 [64][EPS] (34816 B)
  __shared__ __align__(16) char smraw[64 * EPS * 4];
  __shared__ __align__(16) float sfreq[128];

  const int t = blockIdx.y;
  const int cnt = ctr[t];
  const int off = ctr[4 + t];
  const int ntiles = (cnt + 63) >> 6;
  const int chunk = (ntiles + GX - 1) / GX;
  const int t0 = blockIdx.x * chunk;
  const int t1 = min(t0 + chunk, ntiles);
  if (t0 >= t1) return;

  const int tid = threadIdx.x;
  const int wid = tid >> 6, lane = tid & 63;
  const int bl = lane & 15, bh = lane >> 4;
  const int r = tid >> 2, part = tid & 3;   // 4 threads per A-row; part = 32-elem window

  // W fragments, first MFMA operand (A-layout): lane bl <-> out-col, k-window bh*8
  short8 bfrag[8][2];
  #pragma unroll
  for (int n = 0; n < 2; ++n) {
    const unsigned short* bp =
        Wbf + (((size_t)t * OD + wid * 32 + n * 16 + bl) << 8) + (bh << 3);
    #pragma unroll
    for (int k = 0; k < 8; ++k) bfrag[k][n] = *(const short8*)(bp + k * 32);
  }
  // bias for this lane's cols: col = wid*32 + n*16 + bh*4 + j
  const float4 bv0 = *(const float4*)(biasc + t * OD + wid * 32 + bh * 4);
  const float4 bv1 = *(const float4*)(biasc + t * OD + wid * 32 + 16 + bh * 4);

  if (tid < 128) sfreq[tid] = (tid < TD) ? freqs[t * TD + tid] : 0.f;

  auto stage = [&](const float4* p, float tvv) {
    union { unsigned short s[32]; uint4 v4[4]; } pk;
    union { unsigned short s[32]; uint4 v4[4]; } tk;
    #pragma unroll
    for (int c = 0; c < 8; ++c) {
      pk.s[4 * c + 0] = f2bf(p[c].x); pk.s[4 * c + 1] = f2bf(p[c].y);
      pk.s[4 * c + 2] = f2bf(p[c].z); pk.s[4 * c + 3] = f2bf(p[c].w);
    }
    #pragma unroll
    for (int m = 0; m < 8; ++m) {
      float4 fq = *(const float4*)&sfreq[part * 32 + 4 * m];
      tk.s[4 * m + 0] = f2bf(__cosf(tvv * fq.x));
      tk.s[4 * m + 1] = f2bf(__cosf(tvv * fq.y));
      tk.s[4 * m + 2] = f2bf(__cosf(tvv * fq.z));
      tk.s[4 * m + 3] = f2bf(__cosf(tvv * fq.w));
    }
    #pragma unroll
    for (int j = 0; j < 4; ++j)
      *(uint4*)(smraw + a_off(r, part * 32 + 8 * j)) = pk.v4[j];
    #pragma unroll
    for (int j = 0; j < 4; ++j)
      *(uint4*)(smraw + a_off(r, FD + part * 32 + 8 * j)) = tk.v4[j];
  };

  // ---- prologue ----
  int e_cur = -1; float tv_cur = 0.f;
  {
    const int va = min(64, cnt - t0 * 64);
    if (r < va) { e_cur = bucket[off + t0 * 64 + r]; tv_cur = ts[e_cur]; }
  }
  float4 pf[8];
  if (e_cur >= 0) {
    const float4* src = (const float4*)(feats + (size_t)e_cur * FD + part * 32);
    #pragma unroll
    for (int c = 0; c < 8; ++c) pf[c] = src[c];
  }
  int e_b = -1; float tv_b = 0.f;
  if (t0 + 1 < t1) {
    const int vb = min(64, cnt - (t0 + 1) * 64);
    if (r < vb) { e_b = bucket[off + (t0 + 1) * 64 + r]; tv_b = ts[e_b]; }
  }
  __syncthreads();                    // sfreq visible
  if (e_cur >= 0) stage(pf, tv_cur);

  for (int tt = t0; tt < t1; ++tt) {
    const bool last = (tt == t1 - 1);
    __syncthreads();   // A(tt) ready

    // prefetch feats(tt+1) -> regs; drains at the post-MFMA barrier (rides under MFMA)
    if (!last && e_b >= 0) {
      const float4* src = (const float4*)(feats + (size_t)e_b * FD + part * 32);
      #pragma unroll
      for (int c = 0; c < 8; ++c) pf[c] = src[c];
    }
    // issue idx(tt+2): bucket->ts chain covered by a full iteration
    int e_c = -1; float tv_c = 0.f;
    if (tt + 2 < t1) {
      const int vc = min(64, cnt - (tt + 2) * 64);
      if (r < vc) { e_c = bucket[off + (tt + 2) * 64 + r]; tv_c = ts[e_c]; }
    }

    // ---- MFMA, bias in acc-init ----
    f32x4 acc[4][2];
    #pragma unroll
    for (int rt = 0; rt < 4; ++rt) {
      acc[rt][0][0] = bv0.x; acc[rt][0][1] = bv0.y; acc[rt][0][2] = bv0.z; acc[rt][0][3] = bv0.w;
      acc[rt][1][0] = bv1.x; acc[rt][1][1] = bv1.y; acc[rt][1][2] = bv1.z; acc[rt][1][3] = bv1.w;
    }
    __builtin_amdgcn_s_setprio(1);
    #pragma unroll
    for (int rt = 0; rt < 4; ++rt) {
      #pragma unroll
      for (int k = 0; k < 8; ++k) {
        short8 av = *(const short8*)(smraw + a_off(rt * 16 + bl, k * 32 + bh * 8));
        acc[rt][0] = __builtin_amdgcn_mfma_f32_16x16x32_bf16(bfrag[k][0], av, acc[rt][0], 0, 0, 0);
        acc[rt][1] = __builtin_amdgcn_mfma_f32_16x16x32_bf16(bfrag[k][1], av, acc[rt][1], 0, 0, 0);
      }
    }
    __builtin_amdgcn_s_setprio(0);
    __syncthreads();   // A reads done; prefetch drained; region reusable

    // ---- epilogue write: lane -> row rt*16+bl, slot wid*8+n*4+bh, one b128 each ----
    float* ep = (float*)smraw;
    #pragma unroll
    for (int rt = 0; rt < 4; ++rt) {
      *(f32x4*)(ep + ep_w(rt * 16 + bl, wid * 8 + 0 * 4 + bh)) = acc[rt][0];
      *(f32x4*)(ep + ep_w(rt * 16 + bl, wid * 8 + 1 * 4 + bh)) = acc[rt][1];
    }
    __syncthreads();   // epilogue visible

    // ---- store: thread owns its row's cols part*32..+31 (full-line pattern) ----
    if (e_cur >= 0) {
      float* dst = out + (size_t)e_cur * OD + part * 32;
      #pragma unroll
      for (int c = 0; c < 8; ++c) {
        f32x4 v = *(const f32x4*)(ep + ep_w(r, part * 8 + c));
        *(f32x4*)(dst + 4 * c) = v;
      }
    }

    if (!last) {
      __syncthreads();   // ep reads done; stores drained compactly (clean L2 evictions)
      if (e_b >= 0) stage(pf, tv_b);
      e_cur = e_b; tv_cur = tv_b;
      e_b = e_c; tv_b = tv_c;
    }
  }
}

// correctness fallback if ws is too small for bucketing (fp32 vector path)
__global__ void naive_kernel(const float* __restrict__ feats, const float* __restrict__ ts,
                             const int* __restrict__ types, const float* __restrict__ W,
                             const float* __restrict__ b, const float* __restrict__ temb,
                             const float* __restrict__ freqs, float* __restrict__ out) {
  __shared__ float comb[IND];
  int e = blockIdx.x;
  int t = types[e];
  int tid = threadIdx.x;  // 128 threads
  comb[tid] = feats[(size_t)e * FD + tid];
  if (tid < TD) comb[FD + tid] = __cosf(ts[e] * freqs[t * TD + tid]);
  __syncthreads();
  float acc = b[t * OD + tid] + temb[t * OD + tid];
  for (int k = 0; k < IND; ++k) acc += comb[k] * W[((size_t)t * IND + k) * OD + tid];
  out[(size_t)e * OD + tid] = acc;
}

extern "C" void kernel_launch(void* const* d_in, const int* in_sizes, int n_in,
                              void* d_out, int out_size, void* d_ws, size_t ws_size,
                              hipStream_t stream) {
  const float* feats = (const float*)d_in[0];
  const float* ts    = (const float*)d_in[1];
  const int*   types = (const int*)d_in[2];
  const float* W     = (const float*)d_in[3];
  const float* bb    = (const float*)d_in[4];
  const float* temb  = (const float*)d_in[5];
  const float* freqs = (const float*)d_in[6];
  float* out = (float*)d_out;

  if (ws_size < WS_NEED) {
    naive_kernel<<<E_N, 128, 0, stream>>>(feats, ts, types, W, bb, temb, freqs, out);
    return;
  }

  char* ws = (char*)d_ws;
  int* bucket = (int*)(ws + BUCKET_OFF);
  unsigned short* Wbf = (unsigned short*)(ws + WBF_OFF);
  float* biasc = (float*)(ws + BIASC_OFF);
  int* ctr = (int*)(ws + CTR_OFF);

  init_kernel<<<1, 16, 0, stream>>>(ctr);
  hist_kernel<<<1024, 256, 0, stream>>>(types, ctr, E_N);
  scan_bias_kernel<<<1, 256, 0, stream>>>(ctr, bb, temb, biasc);
  wconv_kernel<<<(NT * OD) / 4, 256, 0, stream>>>(W, Wbf);
  fill_kernel<<<(E_N + 255) / 256, 256, 0, stream>>>(types, bucket, ctr + 8, E_N);
  dim3 g(GX, NT);
  gemm_kernel<<<g, 256, 0, stream>>>(feats, ts, freqs, Wbf, biasc, bucket, ctr, out);
}